// Round 18
// baseline (231.715 us; speedup 1.0000x reference)
//
#include <hip/hip_runtime.h>

// ---------------------------------------------------------------------------
// AttentionBlock: GroupNorm(8 groups) -> 1x1 conv QKV -> softmax attention
//                 -> 1x1 conv proj -> residual.   b=8, c=256, h=w=64 (n=4096)
// All GEMM-shaped compute on v_mfma_f32_32x32x16_bf16 (fp32 accum).
// R18 = R17/R15 + ASYMMETRIC setprio role-split (only change):
//   hv=1 waves get prio 1 during S-phase, hv=0 waves get prio 1 during PV.
//   Goal: break the barrier-induced lockstep so the two waves per SIMD
//   anti-phase (one on LDS/MFMA while the other on VALU softmax).
// ---------------------------------------------------------------------------

typedef __bf16 bf16x8 __attribute__((ext_vector_type(8)));
typedef __bf16 bf16x2_t __attribute__((ext_vector_type(2)));
typedef float  f32x16 __attribute__((ext_vector_type(16)));
typedef unsigned short ushort_t;

// 0.0625 * log2(e)
#define QSCALE 0.09016844005556021f
// 8 * log2(e): defer-max threshold in log2 domain
#define THR_L2 11.541560327111707f

__device__ __forceinline__ unsigned short f2b(float f) {
  return __builtin_bit_cast(unsigned short, (__bf16)f);   // native v_cvt (RNE)
}
__device__ __forceinline__ unsigned pk2(float lo, float hi) {
  bf16x2_t p; p[0] = (__bf16)lo; p[1] = (__bf16)hi;       // v_cvt_pk_bf16_f32
  return __builtin_bit_cast(unsigned, p);
}
__device__ __forceinline__ f32x16 zero16() {
  f32x16 z;
#pragma unroll
  for (int i = 0; i < 16; ++i) z[i] = 0.f;
  return z;
}
__device__ __forceinline__ void gl_lds16(const void* gsrc, void* ldst) {
  __builtin_amdgcn_global_load_lds(
      (const __attribute__((address_space(1))) unsigned int*)gsrc,
      (__attribute__((address_space(3))) unsigned int*)ldst, 16, 0, 0);
}

// workspace layout (bytes)
static const size_t OFF_PART = 0;                         // 1024 f32 partial sums
static const size_t OFF_WQ   = 4096;                      // 768*256 bf16 (frag order)
static const size_t OFF_WP   = OFF_WQ + 768*256*2;        // 256*256 bf16 (frag order)
static const size_t OFF_XNT  = OFF_WP + 256*256*2;        // [8] frag-order X' (16MB)
static const size_t OFF_Q    = OFF_XNT + (size_t)8*4096*256*2;
static const size_t OFF_K    = OFF_Q  + (size_t)8*4096*256*2;
static const size_t OFF_V    = OFF_K  + (size_t)8*4096*256*2;   // channel-major [8][256][4096]
static const size_t OFF_O    = OFF_XNT;                   // alias: X' dead after QKV

// ---------------------------------------------------------------------------
// 1) weights fp32 -> bf16, written in MFMA fragment order.
__global__ __launch_bounds__(256) void k_wconv(const float* wq, const float* wp,
                                               ushort_t* wqb, ushort_t* wpb) {
  int t = blockIdx.x * 256 + threadIdx.x;
  if (t < 24576) {                             // 768*256/8
    int lane = t & 63, k = (t >> 6) & 15, tile = t >> 10;
    const float* src = wq + (size_t)(tile*32 + (lane & 31))*256 + (k*2 + (lane >> 5))*8;
    ushort4 lo, hi;
    lo.x = f2b(src[0]); lo.y = f2b(src[1]); lo.z = f2b(src[2]); lo.w = f2b(src[3]);
    hi.x = f2b(src[4]); hi.y = f2b(src[5]); hi.z = f2b(src[6]); hi.w = f2b(src[7]);
    *(ushort4*)(wqb + (size_t)t*8)     = lo;
    *(ushort4*)(wqb + (size_t)t*8 + 4) = hi;
  }
  if (t < 8192) {                              // 256*256/8
    int lane = t & 63, k = (t >> 6) & 15, tile = t >> 10;
    const float* src = wp + (size_t)(tile*32 + (lane & 31))*256 + (k*2 + (lane >> 5))*8;
    ushort4 lo, hi;
    lo.x = f2b(src[0]); lo.y = f2b(src[1]); lo.z = f2b(src[2]); lo.w = f2b(src[3]);
    hi.x = f2b(src[4]); hi.y = f2b(src[5]); hi.z = f2b(src[6]); hi.w = f2b(src[7]);
    *(ushort4*)(wpb + (size_t)t*8)     = lo;
    *(ushort4*)(wpb + (size_t)t*8 + 4) = hi;
  }
}

// ---------------------------------------------------------------------------
// 2) groupnorm partial sums: 64 (b,g) groups x 8 slices, deterministic
__global__ __launch_bounds__(256) void k_stats(const float* x, float* part) {
  int bg = blockIdx.x >> 3, sl = blockIdx.x & 7;
  const float4* p = (const float4*)(x + (size_t)bg*131072u + (size_t)sl*16384u);
  float s = 0.f, ss = 0.f;
  for (int i = threadIdx.x; i < 4096; i += 256) {
    float4 v = p[i];
    s  += (v.x + v.y) + (v.z + v.w);
    ss += (v.x*v.x + v.y*v.y) + (v.z*v.z + v.w*v.w);
  }
#pragma unroll
  for (int m = 1; m < 64; m <<= 1) { s += __shfl_xor(s, m); ss += __shfl_xor(ss, m); }
  __shared__ float ls[4], lq[4];
  int w = threadIdx.x >> 6;
  if ((threadIdx.x & 63) == 0) { ls[w] = s; lq[w] = ss; }
  __syncthreads();
  if (threadIdx.x == 0) {
    part[bg*8 + sl]       = ls[0] + ls[1] + ls[2] + ls[3];
    part[512 + bg*8 + sl] = lq[0] + lq[1] + lq[2] + lq[3];
  }
}

// ---------------------------------------------------------------------------
// 3) normalize + transpose -> X' in B-fragment order
__global__ __launch_bounds__(256) void k_norm_t(const float* x, const float* part,
                                                const float* gw, const float* gb,
                                                ushort_t* xnt) {
  int id = blockIdx.x;
  int b = id & 7, nb = (id >> 3) & 127, cb = id >> 10;   // cb = group
  int bg = b*8 + cb;
  float s = 0.f, q = 0.f;
#pragma unroll
  for (int i = 0; i < 8; ++i) { s += part[bg*8+i]; q += part[512 + bg*8+i]; }
  const float inv_n = 1.f/131072.f;
  float mean = s * inv_n;
  float rstd = rsqrtf(q*inv_n - mean*mean + 1e-5f);

  __shared__ float tile[32][33];
  int tx = threadIdx.x & 31, ty = threadIdx.x >> 5;
  const float* xp = x + ((size_t)b*256 + cb*32)*4096 + nb*32;
#pragma unroll
  for (int r = 0; r < 4; ++r) {
    int cl = ty + r*8;
    int c  = cb*32 + cl;
    float v = xp[(size_t)cl*4096 + tx];
    tile[cl][tx] = (v - mean)*rstd*gw[c] + gb[c];
  }
  __syncthreads();
  int nl = threadIdx.x >> 3, c4 = (threadIdx.x & 7)*4;   // token nl, group-ch c4..+3
  ushort4 o;
  o.x = f2b(tile[c4+0][nl]); o.y = f2b(tile[c4+1][nl]);
  o.z = f2b(tile[c4+2][nl]); o.w = f2b(tile[c4+3][nl]);
  int c0g = cb*32 + c4;                        // global channel (c0g&7 in {0,4})
  size_t addr = (size_t)((nb*16 + (c0g >> 4))*64 + nl + 32*((c0g >> 3) & 1))*8 + (c0g & 7);
  *(ushort4*)(xnt + (size_t)b*1048576 + addr) = o;
}

// ---------------------------------------------------------------------------
// 4) QKV GEMM:  D[o][p] = sum_c W[o][c] * X'[p][c]  (+bias)
__global__ __launch_bounds__(256, 2) void k_qkv(const ushort_t* xnt, const ushort_t* wqb,
                                                const float* qkvb,
                                                ushort_t* qt, ushort_t* kt, ushort_t* vc) {
  int id = blockIdx.x;
  int b = id & 7, rest = id >> 3;
  int nb = rest & 63, ob = rest >> 6;
  int lane = threadIdx.x & 63, w = threadIdx.x >> 6;
  int ln = lane & 31, h = lane >> 5;
  int o0 = ob*128 + w*32;
  int p0 = nb*64;

  const ushort_t* abase = wqb + (size_t)(ob*4 + w)*8192 + lane*8;
  bf16x8 af[16];
#pragma unroll
  for (int k = 0; k < 16; ++k) af[k] = *(const bf16x8*)(abase + k*512);

  const ushort_t* xb = xnt + (size_t)b*1048576 + (size_t)(nb*2)*8192 + lane*8;
  f32x16 acc0 = zero16(), acc1 = zero16();
#pragma unroll
  for (int k = 0; k < 16; ++k) {
    bf16x8 b0 = *(const bf16x8*)(xb + k*512);
    bf16x8 b1 = *(const bf16x8*)(xb + 8192 + k*512);
    acc0 = __builtin_amdgcn_mfma_f32_32x32x16_bf16(af[k], b0, acc0, 0, 0, 0);
    acc1 = __builtin_amdgcn_mfma_f32_32x32x16_bf16(af[k], b1, acc1, 0, 0, 0);
  }
  int sect = o0 >> 8;
#pragma unroll
  for (int jt = 0; jt < 2; ++jt) {
    f32x16 a = jt ? acc1 : acc0;
    int p = p0 + jt*32 + ln;
#pragma unroll
    for (int rg = 0; rg < 4; ++rg) {
      int ob4 = o0 + rg*8 + h*4;
      float4 bi = *(const float4*)(qkvb + ob4);
      float v0 = a[rg*4+0] + bi.x, v1 = a[rg*4+1] + bi.y;
      float v2 = a[rg*4+2] + bi.z, v3 = a[rg*4+3] + bi.w;
      if (sect == 0) {
        v0 *= QSCALE; v1 *= QSCALE; v2 *= QSCALE; v3 *= QSCALE;
        ushort4 st; st.x = f2b(v0); st.y = f2b(v1); st.z = f2b(v2); st.w = f2b(v3);
        *(ushort4*)(qt + ((size_t)b*4096 + p)*256 + (ob4 & 255)) = st;
      } else if (sect == 1) {
        ushort4 st; st.x = f2b(v0); st.y = f2b(v1); st.z = f2b(v2); st.w = f2b(v3);
        *(ushort4*)(kt + ((size_t)b*4096 + p)*256 + (ob4 & 255)) = st;
      } else {
        int c0 = ob4 - 512;
        vc[((size_t)b*256 + c0+0)*4096 + p] = f2b(v0);
        vc[((size_t)b*256 + c0+1)*4096 + p] = f2b(v1);
        vc[((size_t)b*256 + c0+2)*4096 + p] = f2b(v2);
        vc[((size_t)b*256 + c0+3)*4096 + p] = f2b(v3);
      }
    }
  }
}

// ---------------------------------------------------------------------------
// 5) flash attention: grid = 8b x 32qb, 512 thr / 8 waves (R12 structure).
//    K,V double-buffered via global_load_lds; one barrier/iter; log2 softmax;
//    permlane P-pack. R18: hv-asymmetric setprio to anti-phase wave pairs.
__global__ __launch_bounds__(512, 2) void k_attn(const ushort_t* qt, const ushort_t* kt,
                                                 const ushort_t* vc, ushort_t* ot) {
  int id = blockIdx.x;
  int b = id & 7, qb = id >> 3;                // batch -> XCD locality
  int tid = threadIdx.x;
  int lane = tid & 63, w = tid >> 6;
  int ln = lane & 31, h = lane >> 5;
  int hv = w >> 2;                             // kv piece within window (0/1)
  int qs = w & 3;
  int q0 = qb*128 + qs*32;

  __shared__ uint4 slds[8192];                 // 128 KB: K0,K1 (2048 each), V0,V1

  const bf16x8* qrow = (const bf16x8*)(qt + ((size_t)b*4096 + q0 + ln)*256);
  bf16x8 qf[16];
#pragma unroll
  for (int k = 0; k < 16; ++k) qf[k] = qrow[k*2 + h];

  const ushort_t* kb   = kt + (size_t)b*4096*256;
  const ushort_t* vb_g = vc + (size_t)b*256*4096;

  int swz = (lane & 7) ^ ((lane >> 3) & 7);
  const ushort_t* ksrc = kb + (size_t)(w*8 + (lane >> 3))*256 + swz*8;
  const ushort_t* vsrc = vb_g + swz*8;
  int vrow0 = w*32 + (lane >> 3);

  int lnx = ln & 7;
  int koff_base = (hv*4 + (ln >> 3))*256 + lnx*8;

  f32x16 po[8];
#pragma unroll
  for (int t = 0; t < 8; ++t) po[t] = zero16();
  float m_run = -1e30f, l_run = 0.f;

  // prologue: DMA window 0 into buffer 0
#pragma unroll
  for (int q = 0; q < 4; ++q)
    gl_lds16(ksrc + q*64, &slds[w*256 + q*64]);
#pragma unroll
  for (int q = 0; q < 4; ++q)
    gl_lds16(vsrc + (size_t)(vrow0 + q*8)*4096, &slds[4096 + w*256 + q*64]);

  for (int it = 0; it < 64; ++it) {
    int cur = it & 1, nxt = cur ^ 1;
    __syncthreads();   // drains DMA for window it; prev reads of buf[nxt] done

    if (it < 63) {
      int nmb = (it + 1)*64;
#pragma unroll
      for (int q = 0; q < 4; ++q)
        gl_lds16(ksrc + (size_t)nmb*256 + q*64, &slds[nxt*2048 + w*256 + q*64]);
#pragma unroll
      for (int q = 0; q < 4; ++q)
        gl_lds16(vsrc + (size_t)(vrow0 + q*8)*4096 + nmb,
                 &slds[4096 + nxt*2048 + w*256 + q*64]);
    }

    // S^T (log2-domain scores): hv=1 waves get priority -> they finish S
    // first and run softmax (VALU) while hv=0 waves still stream K (LDS).
    const uint4* kbase = &slds[cur*2048 + koff_base];
    f32x16 s0 = zero16();
    if (hv) __builtin_amdgcn_s_setprio(1);
#pragma unroll
    for (int k = 0; k < 16; ++k) {
      int j = k*2 + h;
      bf16x8 kf = *(const bf16x8*)&kbase[(j >> 3)*64 + ((j & 7) ^ lnx)];
      s0 = __builtin_amdgcn_mfma_f32_32x32x16_bf16(kf, qf[k], s0, 0, 0, 0);
    }
    if (hv) __builtin_amdgcn_s_setprio(0);

    // online softmax, log2 domain, defer-max
    float tmax = s0[0];
#pragma unroll
    for (int r = 1; r < 16; ++r) tmax = fmaxf(tmax, s0[r]);
    tmax = fmaxf(tmax, __shfl_xor(tmax, 32));
    if (__any(tmax > m_run + THR_L2)) {
      float nm    = fmaxf(m_run, tmax);
      float alpha = exp2f(m_run - nm);
      m_run = nm;
      l_run *= alpha;
#pragma unroll
      for (int t = 0; t < 8; ++t)
#pragma unroll
        for (int r = 0; r < 16; ++r) po[t][r] *= alpha;
    }
    float psum = 0.f;
#pragma unroll
    for (int r = 0; r < 16; ++r) {
      s0[r] = exp2f(s0[r] - m_run);
      psum += s0[r];
    }
    psum += __shfl_xor(psum, 32);
    l_run += psum;

    // P-pack: native cvt_pk + non-volatile permlane32_swap (VALU, not LDS).
    unsigned p01 = pk2(s0[0],  s0[1]),  p23 = pk2(s0[2],  s0[3]);
    unsigned p45 = pk2(s0[4],  s0[5]),  p67 = pk2(s0[6],  s0[7]);
    unsigned p89 = pk2(s0[8],  s0[9]),  pAB = pk2(s0[10], s0[11]);
    unsigned pCD = pk2(s0[12], s0[13]), pEF = pk2(s0[14], s0[15]);
    asm("v_permlane32_swap_b32 %0, %1" : "+v"(p01), "+v"(p45));
    asm("v_permlane32_swap_b32 %0, %1" : "+v"(p23), "+v"(p67));
    asm("v_permlane32_swap_b32 %0, %1" : "+v"(p89), "+v"(pCD));
    asm("v_permlane32_swap_b32 %0, %1" : "+v"(pAB), "+v"(pEF));
    union { unsigned u[4]; bf16x8 v; } flo, fhi;
    flo.u[0] = p01; flo.u[1] = p23; flo.u[2] = p45; flo.u[3] = p67;
    fhi.u[0] = p89; fhi.u[1] = pAB; fhi.u[2] = pCD; fhi.u[3] = pEF;

    // PV: hv=0 waves get priority (inverse role split).
    const uint4* vbase = &slds[4096 + cur*2048];
    if (!hv) __builtin_amdgcn_s_setprio(1);
#pragma unroll
    for (int ct = 0; ct < 8; ++ct) {
      int c = ct*32 + ln;
      bf16x8 va  = *(const bf16x8*)&vbase[(c*8 + hv*4 + 0 + h) ^ (c & 7)];
      po[ct] = __builtin_amdgcn_mfma_f32_32x32x16_bf16(va, flo.v, po[ct], 0, 0, 0);
      bf16x8 vb2 = *(const bf16x8*)&vbase[(c*8 + hv*4 + 2 + h) ^ (c & 7)];
      po[ct] = __builtin_amdgcn_mfma_f32_32x32x16_bf16(vb2, fhi.v, po[ct], 0, 0, 0);
    }
    if (!hv) __builtin_amdgcn_s_setprio(0);
  }

  // ---- merge kv-pieces: wave pairs (qs, qs+4) share a q-subtile ----
  float* fbuf = (float*)slds;                  // K0 region (dead)
  float* mlb  = fbuf + 8192;                   // K1 region (dead)
  ushort_t* orow = ot + ((size_t)b*4096 + q0 + ln)*256;

#pragma unroll
  for (int rnd = 0; rnd < 4; ++rnd) {
    __syncthreads();
    if (w == rnd + 4) {
#pragma unroll
      for (int t = 0; t < 8; ++t)
#pragma unroll
        for (int rg = 0; rg < 4; ++rg) {
          float4 d; d.x = po[t][rg*4+0]; d.y = po[t][rg*4+1];
          d.z = po[t][rg*4+2]; d.w = po[t][rg*4+3];
          *(float4*)&fbuf[(t*4+rg)*256 + lane*4] = d;
        }
      mlb[lane] = m_run; mlb[64 + lane] = l_run;
    }
    __syncthreads();
    if (w == rnd) {
      float m2 = mlb[lane], l2 = mlb[64 + lane];
      float m  = fmaxf(m_run, m2);
      float a1 = exp2f(m_run - m), a2 = exp2f(m2 - m);
      float inv = 1.f / (l_run*a1 + l2*a2);
      float f1 = a1*inv, f2 = a2*inv;
#pragma unroll
      for (int ct = 0; ct < 8; ++ct)
#pragma unroll
        for (int rg = 0; rg < 4; ++rg) {
          float4 o2 = *(const float4*)&fbuf[(ct*4+rg)*256 + lane*4];
          ushort4 st;
          st.x = f2b(po[ct][rg*4+0]*f1 + o2.x*f2);
          st.y = f2b(po[ct][rg*4+1]*f1 + o2.y*f2);
          st.z = f2b(po[ct][rg*4+2]*f1 + o2.z*f2);
          st.w = f2b(po[ct][rg*4+3]*f1 + o2.w*f2);
          *(ushort4*)(orow + ct*32 + rg*8 + h*4) = st;
        }
    }
  }
}

// ---------------------------------------------------------------------------
// 6) proj GEMM + bias + residual; W_proj loads from fragment-order wpb.
__global__ __launch_bounds__(256, 2) void k_proj(const ushort_t* ot, const ushort_t* wpb,
                                                 const float* pjb, const float* x, float* y) {
  int id = blockIdx.x;
  int b = id & 7, rest = id >> 3;
  int pb = rest & 31, nb = rest >> 5;
  int lane = threadIdx.x & 63, w = threadIdx.x >> 6;
  int ln = lane & 31, h = lane >> 5;
  int p0 = pb*128 + w*32;

  const bf16x8* arow = (const bf16x8*)(ot + ((size_t)b*4096 + p0 + ln)*256);
  bf16x8 af[16];
#pragma unroll
  for (int k = 0; k < 16; ++k) af[k] = arow[k*2 + h];

  const ushort_t* wb = wpb + (size_t)(nb*2)*8192 + lane*8;
  f32x16 acc0 = zero16(), acc1 = zero16();
#pragma unroll
  for (int k = 0; k < 16; ++k) {
    bf16x8 w0 = *(const bf16x8*)(wb + k*512);
    bf16x8 w1 = *(const bf16x8*)(wb + 8192 + k*512);
    acc0 = __builtin_amdgcn_mfma_f32_32x32x16_bf16(af[k], w0, acc0, 0, 0, 0);
    acc1 = __builtin_amdgcn_mfma_f32_32x32x16_bf16(af[k], w1, acc1, 0, 0, 0);
  }
#pragma unroll
  for (int jt = 0; jt < 2; ++jt) {
    f32x16 a = jt ? acc1 : acc0;
    int o = nb*64 + jt*32 + ln;
    float bias = pjb[o];
    const float* xr = x + ((size_t)b*256 + o)*4096;
    float* yr = y + ((size_t)b*256 + o)*4096;
#pragma unroll
    for (int rg = 0; rg < 4; ++rg) {
      int pbase = p0 + rg*8 + h*4;
      float4 xv = *(const float4*)(xr + pbase);
      float4 ov;
      ov.x = xv.x + a[rg*4+0] + bias;
      ov.y = xv.y + a[rg*4+1] + bias;
      ov.z = xv.z + a[rg*4+2] + bias;
      ov.w = xv.w + a[rg*4+3] + bias;
      *(float4*)(yr + pbase) = ov;
    }
  }
}

// ---------------------------------------------------------------------------
extern "C" void kernel_launch(void* const* d_in, const int* in_sizes, int n_in,
                              void* d_out, int out_size, void* d_ws, size_t ws_size,
                              hipStream_t stream) {
  const float* x  = (const float*)d_in[0];
  const float* gw = (const float*)d_in[1];
  const float* gb = (const float*)d_in[2];
  const float* qw = (const float*)d_in[3];
  const float* qb = (const float*)d_in[4];
  const float* pw = (const float*)d_in[5];
  const float* pb = (const float*)d_in[6];

  char* ws = (char*)d_ws;
  float*    part = (float*)(ws + OFF_PART);
  ushort_t* wqb  = (ushort_t*)(ws + OFF_WQ);
  ushort_t* wpb  = (ushort_t*)(ws + OFF_WP);
  ushort_t* xnt  = (ushort_t*)(ws + OFF_XNT);
  ushort_t* qt   = (ushort_t*)(ws + OFF_Q);
  ushort_t* kt   = (ushort_t*)(ws + OFF_K);
  ushort_t* vc   = (ushort_t*)(ws + OFF_V);
  ushort_t* ot   = (ushort_t*)(ws + OFF_O);
  float* y = (float*)d_out;

  k_wconv <<<96,   256, 0, stream>>>(qw, pw, wqb, wpb);
  k_stats <<<512,  256, 0, stream>>>(x, part);
  k_norm_t<<<8192, 256, 0, stream>>>(x, part, gw, gb, xnt);
  k_qkv   <<<3072, 256, 0, stream>>>(xnt, wqb, qb, qt, kt, vc);
  k_attn  <<<256,  512, 0, stream>>>(qt, kt, vc, ot);
  k_proj  <<<1024, 256, 0, stream>>>(ot, wpb, pb, x, y);
}

// Round 19
// 230.343 us; speedup vs baseline: 1.0060x; 1.0060x over previous
//
#include <hip/hip_runtime.h>

// ---------------------------------------------------------------------------
// AttentionBlock: GroupNorm(8 groups) -> 1x1 conv QKV -> softmax attention
//                 -> 1x1 conv proj -> residual.   b=8, c=256, h=w=64 (n=4096)
// All GEMM-shaped compute on v_mfma_f32_32x32x16_bf16 (fp32 accum).
// R19 = R17/R15 verbatim (final form; R18's null prio-split removed).
//   Session-best: total 230.5us; k_attn 165.5us, MfmaUtil 37%.
//   Key structure: coalesced global_load_lds K/V double-buffer (1 barrier/
//   iter), fragment-order W/X' pre-layout, log2-domain softmax + defer-max,
//   cvt_pk + permlane32_swap P-pack.
// ---------------------------------------------------------------------------

typedef __bf16 bf16x8 __attribute__((ext_vector_type(8)));
typedef __bf16 bf16x2_t __attribute__((ext_vector_type(2)));
typedef float  f32x16 __attribute__((ext_vector_type(16)));
typedef unsigned short ushort_t;

// 0.0625 * log2(e)
#define QSCALE 0.09016844005556021f
// 8 * log2(e): defer-max threshold in log2 domain
#define THR_L2 11.541560327111707f

__device__ __forceinline__ unsigned short f2b(float f) {
  return __builtin_bit_cast(unsigned short, (__bf16)f);   // native v_cvt (RNE)
}
__device__ __forceinline__ unsigned pk2(float lo, float hi) {
  bf16x2_t p; p[0] = (__bf16)lo; p[1] = (__bf16)hi;       // v_cvt_pk_bf16_f32
  return __builtin_bit_cast(unsigned, p);
}
__device__ __forceinline__ f32x16 zero16() {
  f32x16 z;
#pragma unroll
  for (int i = 0; i < 16; ++i) z[i] = 0.f;
  return z;
}
__device__ __forceinline__ void gl_lds16(const void* gsrc, void* ldst) {
  __builtin_amdgcn_global_load_lds(
      (const __attribute__((address_space(1))) unsigned int*)gsrc,
      (__attribute__((address_space(3))) unsigned int*)ldst, 16, 0, 0);
}

// workspace layout (bytes)
static const size_t OFF_PART = 0;                         // 1024 f32 partial sums
static const size_t OFF_WQ   = 4096;                      // 768*256 bf16 (frag order)
static const size_t OFF_WP   = OFF_WQ + 768*256*2;        // 256*256 bf16 (frag order)
static const size_t OFF_XNT  = OFF_WP + 256*256*2;        // [8] frag-order X' (16MB)
static const size_t OFF_Q    = OFF_XNT + (size_t)8*4096*256*2;
static const size_t OFF_K    = OFF_Q  + (size_t)8*4096*256*2;
static const size_t OFF_V    = OFF_K  + (size_t)8*4096*256*2;   // channel-major [8][256][4096]
static const size_t OFF_O    = OFF_XNT;                   // alias: X' dead after QKV

// ---------------------------------------------------------------------------
// 1) weights fp32 -> bf16, written in MFMA fragment order.
__global__ __launch_bounds__(256) void k_wconv(const float* wq, const float* wp,
                                               ushort_t* wqb, ushort_t* wpb) {
  int t = blockIdx.x * 256 + threadIdx.x;
  if (t < 24576) {                             // 768*256/8
    int lane = t & 63, k = (t >> 6) & 15, tile = t >> 10;
    const float* src = wq + (size_t)(tile*32 + (lane & 31))*256 + (k*2 + (lane >> 5))*8;
    ushort4 lo, hi;
    lo.x = f2b(src[0]); lo.y = f2b(src[1]); lo.z = f2b(src[2]); lo.w = f2b(src[3]);
    hi.x = f2b(src[4]); hi.y = f2b(src[5]); hi.z = f2b(src[6]); hi.w = f2b(src[7]);
    *(ushort4*)(wqb + (size_t)t*8)     = lo;
    *(ushort4*)(wqb + (size_t)t*8 + 4) = hi;
  }
  if (t < 8192) {                              // 256*256/8
    int lane = t & 63, k = (t >> 6) & 15, tile = t >> 10;
    const float* src = wp + (size_t)(tile*32 + (lane & 31))*256 + (k*2 + (lane >> 5))*8;
    ushort4 lo, hi;
    lo.x = f2b(src[0]); lo.y = f2b(src[1]); lo.z = f2b(src[2]); lo.w = f2b(src[3]);
    hi.x = f2b(src[4]); hi.y = f2b(src[5]); hi.z = f2b(src[6]); hi.w = f2b(src[7]);
    *(ushort4*)(wpb + (size_t)t*8)     = lo;
    *(ushort4*)(wpb + (size_t)t*8 + 4) = hi;
  }
}

// ---------------------------------------------------------------------------
// 2) groupnorm partial sums: 64 (b,g) groups x 8 slices, deterministic
__global__ __launch_bounds__(256) void k_stats(const float* x, float* part) {
  int bg = blockIdx.x >> 3, sl = blockIdx.x & 7;
  const float4* p = (const float4*)(x + (size_t)bg*131072u + (size_t)sl*16384u);
  float s = 0.f, ss = 0.f;
  for (int i = threadIdx.x; i < 4096; i += 256) {
    float4 v = p[i];
    s  += (v.x + v.y) + (v.z + v.w);
    ss += (v.x*v.x + v.y*v.y) + (v.z*v.z + v.w*v.w);
  }
#pragma unroll
  for (int m = 1; m < 64; m <<= 1) { s += __shfl_xor(s, m); ss += __shfl_xor(ss, m); }
  __shared__ float ls[4], lq[4];
  int w = threadIdx.x >> 6;
  if ((threadIdx.x & 63) == 0) { ls[w] = s; lq[w] = ss; }
  __syncthreads();
  if (threadIdx.x == 0) {
    part[bg*8 + sl]       = ls[0] + ls[1] + ls[2] + ls[3];
    part[512 + bg*8 + sl] = lq[0] + lq[1] + lq[2] + lq[3];
  }
}

// ---------------------------------------------------------------------------
// 3) normalize + transpose -> X' in B-fragment order
__global__ __launch_bounds__(256) void k_norm_t(const float* x, const float* part,
                                                const float* gw, const float* gb,
                                                ushort_t* xnt) {
  int id = blockIdx.x;
  int b = id & 7, nb = (id >> 3) & 127, cb = id >> 10;   // cb = group
  int bg = b*8 + cb;
  float s = 0.f, q = 0.f;
#pragma unroll
  for (int i = 0; i < 8; ++i) { s += part[bg*8+i]; q += part[512 + bg*8+i]; }
  const float inv_n = 1.f/131072.f;
  float mean = s * inv_n;
  float rstd = rsqrtf(q*inv_n - mean*mean + 1e-5f);

  __shared__ float tile[32][33];
  int tx = threadIdx.x & 31, ty = threadIdx.x >> 5;
  const float* xp = x + ((size_t)b*256 + cb*32)*4096 + nb*32;
#pragma unroll
  for (int r = 0; r < 4; ++r) {
    int cl = ty + r*8;
    int c  = cb*32 + cl;
    float v = xp[(size_t)cl*4096 + tx];
    tile[cl][tx] = (v - mean)*rstd*gw[c] + gb[c];
  }
  __syncthreads();
  int nl = threadIdx.x >> 3, c4 = (threadIdx.x & 7)*4;   // token nl, group-ch c4..+3
  ushort4 o;
  o.x = f2b(tile[c4+0][nl]); o.y = f2b(tile[c4+1][nl]);
  o.z = f2b(tile[c4+2][nl]); o.w = f2b(tile[c4+3][nl]);
  int c0g = cb*32 + c4;                        // global channel (c0g&7 in {0,4})
  size_t addr = (size_t)((nb*16 + (c0g >> 4))*64 + nl + 32*((c0g >> 3) & 1))*8 + (c0g & 7);
  *(ushort4*)(xnt + (size_t)b*1048576 + addr) = o;
}

// ---------------------------------------------------------------------------
// 4) QKV GEMM:  D[o][p] = sum_c W[o][c] * X'[p][c]  (+bias)
__global__ __launch_bounds__(256, 2) void k_qkv(const ushort_t* xnt, const ushort_t* wqb,
                                                const float* qkvb,
                                                ushort_t* qt, ushort_t* kt, ushort_t* vc) {
  int id = blockIdx.x;
  int b = id & 7, rest = id >> 3;
  int nb = rest & 63, ob = rest >> 6;
  int lane = threadIdx.x & 63, w = threadIdx.x >> 6;
  int ln = lane & 31, h = lane >> 5;
  int o0 = ob*128 + w*32;
  int p0 = nb*64;

  const ushort_t* abase = wqb + (size_t)(ob*4 + w)*8192 + lane*8;
  bf16x8 af[16];
#pragma unroll
  for (int k = 0; k < 16; ++k) af[k] = *(const bf16x8*)(abase + k*512);

  const ushort_t* xb = xnt + (size_t)b*1048576 + (size_t)(nb*2)*8192 + lane*8;
  f32x16 acc0 = zero16(), acc1 = zero16();
#pragma unroll
  for (int k = 0; k < 16; ++k) {
    bf16x8 b0 = *(const bf16x8*)(xb + k*512);
    bf16x8 b1 = *(const bf16x8*)(xb + 8192 + k*512);
    acc0 = __builtin_amdgcn_mfma_f32_32x32x16_bf16(af[k], b0, acc0, 0, 0, 0);
    acc1 = __builtin_amdgcn_mfma_f32_32x32x16_bf16(af[k], b1, acc1, 0, 0, 0);
  }
  int sect = o0 >> 8;
#pragma unroll
  for (int jt = 0; jt < 2; ++jt) {
    f32x16 a = jt ? acc1 : acc0;
    int p = p0 + jt*32 + ln;
#pragma unroll
    for (int rg = 0; rg < 4; ++rg) {
      int ob4 = o0 + rg*8 + h*4;
      float4 bi = *(const float4*)(qkvb + ob4);
      float v0 = a[rg*4+0] + bi.x, v1 = a[rg*4+1] + bi.y;
      float v2 = a[rg*4+2] + bi.z, v3 = a[rg*4+3] + bi.w;
      if (sect == 0) {
        v0 *= QSCALE; v1 *= QSCALE; v2 *= QSCALE; v3 *= QSCALE;
        ushort4 st; st.x = f2b(v0); st.y = f2b(v1); st.z = f2b(v2); st.w = f2b(v3);
        *(ushort4*)(qt + ((size_t)b*4096 + p)*256 + (ob4 & 255)) = st;
      } else if (sect == 1) {
        ushort4 st; st.x = f2b(v0); st.y = f2b(v1); st.z = f2b(v2); st.w = f2b(v3);
        *(ushort4*)(kt + ((size_t)b*4096 + p)*256 + (ob4 & 255)) = st;
      } else {
        int c0 = ob4 - 512;
        vc[((size_t)b*256 + c0+0)*4096 + p] = f2b(v0);
        vc[((size_t)b*256 + c0+1)*4096 + p] = f2b(v1);
        vc[((size_t)b*256 + c0+2)*4096 + p] = f2b(v2);
        vc[((size_t)b*256 + c0+3)*4096 + p] = f2b(v3);
      }
    }
  }
}

// ---------------------------------------------------------------------------
// 5) flash attention: grid = 8b x 32qb, 512 thr / 8 waves (R12 structure).
//    K,V double-buffered via global_load_lds; one barrier/iter; log2 softmax;
//    P-pack via native cvt_pk + non-volatile permlane32_swap.
__global__ __launch_bounds__(512, 2) void k_attn(const ushort_t* qt, const ushort_t* kt,
                                                 const ushort_t* vc, ushort_t* ot) {
  int id = blockIdx.x;
  int b = id & 7, qb = id >> 3;                // batch -> XCD locality
  int tid = threadIdx.x;
  int lane = tid & 63, w = tid >> 6;
  int ln = lane & 31, h = lane >> 5;
  int hv = w >> 2;                             // kv piece within window (0/1)
  int qs = w & 3;
  int q0 = qb*128 + qs*32;

  __shared__ uint4 slds[8192];                 // 128 KB: K0,K1 (2048 each), V0,V1

  const bf16x8* qrow = (const bf16x8*)(qt + ((size_t)b*4096 + q0 + ln)*256);
  bf16x8 qf[16];
#pragma unroll
  for (int k = 0; k < 16; ++k) qf[k] = qrow[k*2 + h];

  const ushort_t* kb   = kt + (size_t)b*4096*256;
  const ushort_t* vb_g = vc + (size_t)b*256*4096;

  int swz = (lane & 7) ^ ((lane >> 3) & 7);
  const ushort_t* ksrc = kb + (size_t)(w*8 + (lane >> 3))*256 + swz*8;
  const ushort_t* vsrc = vb_g + swz*8;
  int vrow0 = w*32 + (lane >> 3);

  int lnx = ln & 7;
  int koff_base = (hv*4 + (ln >> 3))*256 + lnx*8;

  f32x16 po[8];
#pragma unroll
  for (int t = 0; t < 8; ++t) po[t] = zero16();
  float m_run = -1e30f, l_run = 0.f;

  // prologue: DMA window 0 into buffer 0
#pragma unroll
  for (int q = 0; q < 4; ++q)
    gl_lds16(ksrc + q*64, &slds[w*256 + q*64]);
#pragma unroll
  for (int q = 0; q < 4; ++q)
    gl_lds16(vsrc + (size_t)(vrow0 + q*8)*4096, &slds[4096 + w*256 + q*64]);

  for (int it = 0; it < 64; ++it) {
    int cur = it & 1, nxt = cur ^ 1;
    __syncthreads();   // drains DMA for window it; prev reads of buf[nxt] done

    if (it < 63) {
      int nmb = (it + 1)*64;
#pragma unroll
      for (int q = 0; q < 4; ++q)
        gl_lds16(ksrc + (size_t)nmb*256 + q*64, &slds[nxt*2048 + w*256 + q*64]);
#pragma unroll
      for (int q = 0; q < 4; ++q)
        gl_lds16(vsrc + (size_t)(vrow0 + q*8)*4096 + nmb,
                 &slds[4096 + nxt*2048 + w*256 + q*64]);
    }

    // S^T (log2-domain scores) on this wave's 32 kv rows
    const uint4* kbase = &slds[cur*2048 + koff_base];
    f32x16 s0 = zero16();
    __builtin_amdgcn_s_setprio(1);
#pragma unroll
    for (int k = 0; k < 16; ++k) {
      int j = k*2 + h;
      bf16x8 kf = *(const bf16x8*)&kbase[(j >> 3)*64 + ((j & 7) ^ lnx)];
      s0 = __builtin_amdgcn_mfma_f32_32x32x16_bf16(kf, qf[k], s0, 0, 0, 0);
    }
    __builtin_amdgcn_s_setprio(0);

    // online softmax, log2 domain, defer-max
    float tmax = s0[0];
#pragma unroll
    for (int r = 1; r < 16; ++r) tmax = fmaxf(tmax, s0[r]);
    tmax = fmaxf(tmax, __shfl_xor(tmax, 32));
    if (__any(tmax > m_run + THR_L2)) {
      float nm    = fmaxf(m_run, tmax);
      float alpha = exp2f(m_run - nm);
      m_run = nm;
      l_run *= alpha;
#pragma unroll
      for (int t = 0; t < 8; ++t)
#pragma unroll
        for (int r = 0; r < 16; ++r) po[t][r] *= alpha;
    }
    float psum = 0.f;
#pragma unroll
    for (int r = 0; r < 16; ++r) {
      s0[r] = exp2f(s0[r] - m_run);
      psum += s0[r];
    }
    psum += __shfl_xor(psum, 32);
    l_run += psum;

    // P-pack: native cvt_pk + non-volatile permlane32_swap (VALU, not LDS).
    unsigned p01 = pk2(s0[0],  s0[1]),  p23 = pk2(s0[2],  s0[3]);
    unsigned p45 = pk2(s0[4],  s0[5]),  p67 = pk2(s0[6],  s0[7]);
    unsigned p89 = pk2(s0[8],  s0[9]),  pAB = pk2(s0[10], s0[11]);
    unsigned pCD = pk2(s0[12], s0[13]), pEF = pk2(s0[14], s0[15]);
    asm("v_permlane32_swap_b32 %0, %1" : "+v"(p01), "+v"(p45));
    asm("v_permlane32_swap_b32 %0, %1" : "+v"(p23), "+v"(p67));
    asm("v_permlane32_swap_b32 %0, %1" : "+v"(p89), "+v"(pCD));
    asm("v_permlane32_swap_b32 %0, %1" : "+v"(pAB), "+v"(pEF));
    union { unsigned u[4]; bf16x8 v; } flo, fhi;
    flo.u[0] = p01; flo.u[1] = p23; flo.u[2] = p45; flo.u[3] = p67;
    fhi.u[0] = p89; fhi.u[1] = pAB; fhi.u[2] = pCD; fhi.u[3] = pEF;

    const uint4* vbase = &slds[4096 + cur*2048];
    __builtin_amdgcn_s_setprio(1);
#pragma unroll
    for (int ct = 0; ct < 8; ++ct) {
      int c = ct*32 + ln;
      bf16x8 va  = *(const bf16x8*)&vbase[(c*8 + hv*4 + 0 + h) ^ (c & 7)];
      po[ct] = __builtin_amdgcn_mfma_f32_32x32x16_bf16(va, flo.v, po[ct], 0, 0, 0);
      bf16x8 vb2 = *(const bf16x8*)&vbase[(c*8 + hv*4 + 2 + h) ^ (c & 7)];
      po[ct] = __builtin_amdgcn_mfma_f32_32x32x16_bf16(vb2, fhi.v, po[ct], 0, 0, 0);
    }
    __builtin_amdgcn_s_setprio(0);
  }

  // ---- merge kv-pieces: wave pairs (qs, qs+4) share a q-subtile ----
  float* fbuf = (float*)slds;                  // K0 region (dead)
  float* mlb  = fbuf + 8192;                   // K1 region (dead)
  ushort_t* orow = ot + ((size_t)b*4096 + q0 + ln)*256;

#pragma unroll
  for (int rnd = 0; rnd < 4; ++rnd) {
    __syncthreads();
    if (w == rnd + 4) {
#pragma unroll
      for (int t = 0; t < 8; ++t)
#pragma unroll
        for (int rg = 0; rg < 4; ++rg) {
          float4 d; d.x = po[t][rg*4+0]; d.y = po[t][rg*4+1];
          d.z = po[t][rg*4+2]; d.w = po[t][rg*4+3];
          *(float4*)&fbuf[(t*4+rg)*256 + lane*4] = d;
        }
      mlb[lane] = m_run; mlb[64 + lane] = l_run;
    }
    __syncthreads();
    if (w == rnd) {
      float m2 = mlb[lane], l2 = mlb[64 + lane];
      float m  = fmaxf(m_run, m2);
      float a1 = exp2f(m_run - m), a2 = exp2f(m2 - m);
      float inv = 1.f / (l_run*a1 + l2*a2);
      float f1 = a1*inv, f2 = a2*inv;
#pragma unroll
      for (int ct = 0; ct < 8; ++ct)
#pragma unroll
        for (int rg = 0; rg < 4; ++rg) {
          float4 o2 = *(const float4*)&fbuf[(ct*4+rg)*256 + lane*4];
          ushort4 st;
          st.x = f2b(po[ct][rg*4+0]*f1 + o2.x*f2);
          st.y = f2b(po[ct][rg*4+1]*f1 + o2.y*f2);
          st.z = f2b(po[ct][rg*4+2]*f1 + o2.z*f2);
          st.w = f2b(po[ct][rg*4+3]*f1 + o2.w*f2);
          *(ushort4*)(orow + ct*32 + rg*8 + h*4) = st;
        }
    }
  }
}

// ---------------------------------------------------------------------------
// 6) proj GEMM + bias + residual; W_proj loads from fragment-order wpb.
__global__ __launch_bounds__(256, 2) void k_proj(const ushort_t* ot, const ushort_t* wpb,
                                                 const float* pjb, const float* x, float* y) {
  int id = blockIdx.x;
  int b = id & 7, rest = id >> 3;
  int pb = rest & 31, nb = rest >> 5;
  int lane = threadIdx.x & 63, w = threadIdx.x >> 6;
  int ln = lane & 31, h = lane >> 5;
  int p0 = pb*128 + w*32;

  const bf16x8* arow = (const bf16x8*)(ot + ((size_t)b*4096 + p0 + ln)*256);
  bf16x8 af[16];
#pragma unroll
  for (int k = 0; k < 16; ++k) af[k] = arow[k*2 + h];

  const ushort_t* wb = wpb + (size_t)(nb*2)*8192 + lane*8;
  f32x16 acc0 = zero16(), acc1 = zero16();
#pragma unroll
  for (int k = 0; k < 16; ++k) {
    bf16x8 w0 = *(const bf16x8*)(wb + k*512);
    bf16x8 w1 = *(const bf16x8*)(wb + 8192 + k*512);
    acc0 = __builtin_amdgcn_mfma_f32_32x32x16_bf16(af[k], w0, acc0, 0, 0, 0);
    acc1 = __builtin_amdgcn_mfma_f32_32x32x16_bf16(af[k], w1, acc1, 0, 0, 0);
  }
#pragma unroll
  for (int jt = 0; jt < 2; ++jt) {
    f32x16 a = jt ? acc1 : acc0;
    int o = nb*64 + jt*32 + ln;
    float bias = pjb[o];
    const float* xr = x + ((size_t)b*256 + o)*4096;
    float* yr = y + ((size_t)b*256 + o)*4096;
#pragma unroll
    for (int rg = 0; rg < 4; ++rg) {
      int pbase = p0 + rg*8 + h*4;
      float4 xv = *(const float4*)(xr + pbase);
      float4 ov;
      ov.x = xv.x + a[rg*4+0] + bias;
      ov.y = xv.y + a[rg*4+1] + bias;
      ov.z = xv.z + a[rg*4+2] + bias;
      ov.w = xv.w + a[rg*4+3] + bias;
      *(float4*)(yr + pbase) = ov;
    }
  }
}

// ---------------------------------------------------------------------------
extern "C" void kernel_launch(void* const* d_in, const int* in_sizes, int n_in,
                              void* d_out, int out_size, void* d_ws, size_t ws_size,
                              hipStream_t stream) {
  const float* x  = (const float*)d_in[0];
  const float* gw = (const float*)d_in[1];
  const float* gb = (const float*)d_in[2];
  const float* qw = (const float*)d_in[3];
  const float* qb = (const float*)d_in[4];
  const float* pw = (const float*)d_in[5];
  const float* pb = (const float*)d_in[6];

  char* ws = (char*)d_ws;
  float*    part = (float*)(ws + OFF_PART);
  ushort_t* wqb  = (ushort_t*)(ws + OFF_WQ);
  ushort_t* wpb  = (ushort_t*)(ws + OFF_WP);
  ushort_t* xnt  = (ushort_t*)(ws + OFF_XNT);
  ushort_t* qt   = (ushort_t*)(ws + OFF_Q);
  ushort_t* kt   = (ushort_t*)(ws + OFF_K);
  ushort_t* vc   = (ushort_t*)(ws + OFF_V);
  ushort_t* ot   = (ushort_t*)(ws + OFF_O);
  float* y = (float*)d_out;

  k_wconv <<<96,   256, 0, stream>>>(qw, pw, wqb, wpb);
  k_stats <<<512,  256, 0, stream>>>(x, part);
  k_norm_t<<<8192, 256, 0, stream>>>(x, part, gw, gb, xnt);
  k_qkv   <<<3072, 256, 0, stream>>>(xnt, wqb, qb, qt, kt, vc);
  k_attn  <<<256,  512, 0, stream>>>(qt, kt, vc, ot);
  k_proj  <<<1024, 256, 0, stream>>>(ot, wpb, pb, x, y);
}